// Round 1
// 167.211 us; speedup vs baseline: 1.0329x; 1.0329x over previous
//
#include <hip/hip_runtime.h>

#define B_  4
#define N_  4096   // H*W
#define C_  256
#define D_  32

typedef __attribute__((ext_vector_type(8))) short bf8;   // 8 bf16 (4 VGPRs)
typedef __attribute__((ext_vector_type(4))) float f4;    // MFMA C/D frag

__device__ __forceinline__ unsigned short bft(float f) {
    unsigned u = __builtin_bit_cast(unsigned, f);
    return (unsigned short)((u + 0x8000u) >> 16);
}
// pack two floats to bf16x2 (a->low, b->high), round-half-up, 3 VALU ops
__device__ __forceinline__ unsigned pk2(float a, float b) {
    unsigned ua = __builtin_bit_cast(unsigned, a) + 0x8000u;
    unsigned ub = __builtin_bit_cast(unsigned, b) + 0x8000u;
    return __builtin_amdgcn_perm(ub, ua, 0x07060302u);  // bytes {b3,b2,a3,a2}
}

// ---------------------------------------------------------------------------
// prep: weights -> bf16. Wqkb[64][256] = Wq rows 0-31, Wk rows 32-63.
// ---------------------------------------------------------------------------
__global__ __launch_bounds__(256) void prep(
    const float* __restrict__ Wq, const float* __restrict__ Wk,
    const float* __restrict__ Wv,
    unsigned short* __restrict__ Wqkb, unsigned short* __restrict__ Wvb)
{
    int i = blockIdx.x * 256 + threadIdx.x;
    if (i < 8192)       Wqkb[i] = bft(Wq[i]);
    else if (i < 16384) Wqkb[i] = bft(Wk[i - 8192]);
    Wvb[i] = bft(Wv[i]);
}

// ---------------------------------------------------------------------------
// qkv: MFMA projections, coalesced staging. grid(128,4), 256 thr.
// q is pre-scaled by log2(e) so attn can use raw v_exp_f32 (2^x).
// Outputs: qb,kb [B][N][32] bf16 ; vb [B][C][N] bf16.
// ---------------------------------------------------------------------------
__global__ __launch_bounds__(256) void qkv(
    const float* __restrict__ x,
    const unsigned short* __restrict__ Wqkb, const unsigned short* __restrict__ Wvb,
    const float* __restrict__ bq, const float* __restrict__ bk,
    const float* __restrict__ bv,
    unsigned short* __restrict__ qb, unsigned short* __restrict__ kb,
    unsigned short* __restrict__ vb)
{
    const int b = blockIdx.y, n0 = blockIdx.x * 32;
    const int t = threadIdx.x;
    const int lane = t & 63, w = t >> 6, c15 = lane & 15, g = lane >> 4;

    __shared__ __align__(16) unsigned short xs[32][264];

    // coalesced stage + transpose: 8 lanes cover one 128-B row segment
    {
        const int r = t >> 3, cg = t & 7;
        #pragma unroll
        for (int it = 0; it < 8; ++it) {
            int c = r + 32 * it;
            float4 v = *(const float4*)(x + ((size_t)(b * C_ + c)) * N_ + n0 + cg * 4);
            xs[cg * 4 + 0][c] = bft(v.x);
            xs[cg * 4 + 1][c] = bft(v.y);
            xs[cg * 4 + 2][c] = bft(v.z);
            xs[cg * 4 + 3][c] = bft(v.w);
        }
    }
    __syncthreads();

    f4 qkacc[2]; f4 vacc[2][4];
    const f4 fz = {0.f, 0.f, 0.f, 0.f};
    qkacc[0] = fz; qkacc[1] = fz;
    #pragma unroll
    for (int nt = 0; nt < 2; ++nt)
        #pragma unroll
        for (int ct = 0; ct < 4; ++ct) vacc[nt][ct] = fz;

    const unsigned short* wqk = Wqkb + (w * 16 + c15) * C_ + g * 8;
    const unsigned short* wv0 = Wvb + (w * 64 + c15) * C_ + g * 8;
    const unsigned short* xsp = &xs[c15][g * 8];

    #pragma unroll
    for (int ks = 0; ks < 8; ++ks) {
        bf8 xf0 = *(const bf8*)(xsp + ks * 32);
        bf8 xf1 = *(const bf8*)(xsp + 16 * 264 + ks * 32);
        bf8 af  = *(const bf8*)(wqk + ks * 32);
        qkacc[0] = __builtin_amdgcn_mfma_f32_16x16x32_bf16(af, xf0, qkacc[0], 0, 0, 0);
        qkacc[1] = __builtin_amdgcn_mfma_f32_16x16x32_bf16(af, xf1, qkacc[1], 0, 0, 0);
        #pragma unroll
        for (int ct = 0; ct < 4; ++ct) {
            bf8 bfv = *(const bf8*)(wv0 + ct * 16 * C_ + ks * 32);
            vacc[0][ct] = __builtin_amdgcn_mfma_f32_16x16x32_bf16(xf0, bfv, vacc[0][ct], 0, 0, 0);
            vacc[1][ct] = __builtin_amdgcn_mfma_f32_16x16x32_bf16(xf1, bfv, vacc[1][ct], 0, 0, 0);
        }
    }

    // epilogue q/k (q scaled by log2e for exp2-softmax)
    {
        float4 bias = (w < 2) ? *(const float4*)(bq + (w & 1) * 16 + 4 * g)
                              : *(const float4*)(bk + (w & 1) * 16 + 4 * g);
        float sc = (w < 2) ? 1.44269504f : 1.0f;
        unsigned short* base = (w < 2) ? qb : kb;
        int d0 = (w & 1) * 16 + 4 * g;
        #pragma unroll
        for (int nt = 0; nt < 2; ++nt) {
            int n = n0 + nt * 16 + c15;
            f4 a = qkacc[nt];
            uint2 pk;
            pk.x = pk2((a.x + bias.x) * sc, (a.y + bias.y) * sc);
            pk.y = pk2((a.z + bias.z) * sc, (a.w + bias.w) * sc);
            *(uint2*)(base + ((size_t)(b * N_ + n)) * D_ + d0) = pk;
        }
    }
    // epilogue v
    #pragma unroll
    for (int ct = 0; ct < 4; ++ct) {
        int cout = w * 64 + ct * 16 + c15;
        float bvv = bv[cout];
        #pragma unroll
        for (int nt = 0; nt < 2; ++nt) {
            f4 a = vacc[nt][ct];
            uint2 pk;
            pk.x = pk2(a.x + bvv, a.y + bvv);
            pk.y = pk2(a.z + bvv, a.w + bvv);
            *(uint2*)(vb + ((size_t)(b * C_ + cout)) * (size_t)N_ + n0 + nt * 16 + 4 * g) = pk;
        }
    }
}

// ---------------------------------------------------------------------------
// attn v2: flash MFMA attention, M=64 queries, c-half=128, KT=128 per iter.
// grid(512) = 2 blocks/CU (the key change: independent co-resident blocks
// overlap produce-VALU with consume-MFMA phases). 512 thr (8 waves).
// bid&7 = (b, c-half) so each XCD's L2 holds exactly one 1MB V-slice.
// Ps is XOR-swizzled (byte ^= (row&7)<<4): conflict-free b128 reads and
// b64 writes (derived: 8 lanes / 4-bank group on reads, 4 words/bank writes).
// produce: wave w owns n-frag w (4 m-frags, 4 MFMA).
// consume: wave (cq=w&3, ksh=w>>2): 4mt x 2ct tile, k-half; ksh halves
// combined through LDS at the end. Light asm barrier keeps K/V prefetch
// loads in flight across it.
// ---------------------------------------------------------------------------
__global__ __launch_bounds__(512, 4) void attn(
    const unsigned short* __restrict__ qb, const unsigned short* __restrict__ kb,
    const unsigned short* __restrict__ vb, const float* __restrict__ x,
    const float* __restrict__ gamma, float* __restrict__ out)
{
    const int bid = blockIdx.x;
    const int combo = bid & 7, mb = bid >> 3;
    const int b = combo >> 1, c0 = (combo & 1) * 128, m0 = mb * 64;
    const int t = threadIdx.x;
    const int lane = t & 63, w = t >> 6, c15 = lane & 15, g = lane >> 4;
    const int cq = w & 3, ksh = w >> 2;          // consume role
    const int sw = (c15 & 7) << 4;               // LDS XOR swizzle (bits 4-6)

    __shared__ __align__(16) unsigned short Ps[2][64 * 128]; // 256-B rows, swizzled
    __shared__ float l_s[8][64];
    __shared__ __align__(16) float l_tot[64];

    const f4 fz = {0.f, 0.f, 0.f, 0.f};

    bf8 qf[4];
    #pragma unroll
    for (int mi = 0; mi < 4; ++mi)
        qf[mi] = *(const bf8*)(qb + ((size_t)(b * N_ + m0 + mi * 16 + c15)) * D_ + g * 8);

    bf8 kf = *(const bf8*)(kb + ((size_t)(b * N_ + w * 16 + c15)) * D_ + g * 8);

    f4 acc[4][2];
    #pragma unroll
    for (int mt = 0; mt < 4; ++mt)
        #pragma unroll
        for (int ct = 0; ct < 2; ++ct) acc[mt][ct] = fz;
    float lrun[4] = {0.f, 0.f, 0.f, 0.f};

    const unsigned short* vbase = vb + ((size_t)(b * C_ + c0 + cq * 32)) * (size_t)N_;

    for (int j0 = 0; j0 < N_; j0 += 128) {
        const int buf = (j0 >> 7) & 1;
        char* pbase = (char*)Ps[buf];
        // V prefetch for this iter's consume (stays in flight across barrier)
        bf8 vf[2][2];
        #pragma unroll
        for (int ki = 0; ki < 2; ++ki)
            #pragma unroll
            for (int ct = 0; ct < 2; ++ct)
                vf[ki][ct] = *(const bf8*)(vbase + (size_t)(ct * 16 + c15) * N_
                                           + j0 + ksh * 64 + ki * 32 + g * 8);
        // produce S^T = K·Q^T for this wave's 16-col n-frag
        f4 s[4];
        #pragma unroll
        for (int mi = 0; mi < 4; ++mi)
            s[mi] = __builtin_amdgcn_mfma_f32_16x16x32_bf16(kf, qf[mi], fz, 0, 0, 0);
        // K prefetch for next iter
        if (j0 + 128 < N_)
            kf = *(const bf8*)(kb + ((size_t)(b * N_ + j0 + 128 + w * 16 + c15)) * D_ + g * 8);
        // exp2 (q pre-scaled by log2e), pack, write P (swizzled)
        #pragma unroll
        for (int mi = 0; mi < 4; ++mi) {
            float p0 = __builtin_amdgcn_exp2f(s[mi].x);
            float p1 = __builtin_amdgcn_exp2f(s[mi].y);
            float p2 = __builtin_amdgcn_exp2f(s[mi].z);
            float p3 = __builtin_amdgcn_exp2f(s[mi].w);
            lrun[mi] += (p0 + p1) + (p2 + p3);
            uint2 pk; pk.x = pk2(p0, p1); pk.y = pk2(p2, p3);
            *(uint2*)(pbase + (mi * 16 + c15) * 256 + ((w * 32 + 8 * g) ^ sw)) = pk;
        }
        // light barrier: drain LDS writes only; global loads stay in flight
        asm volatile("s_waitcnt lgkmcnt(0)\n\ts_barrier" ::: "memory");
        // consume: O += P·V^T, this wave's 64m x 32c tile, ks-half
        #pragma unroll
        for (int ki = 0; ki < 2; ++ki) {
            const int kbyte = (ksh * 128 + ki * 64 + 16 * g) ^ sw;
            bf8 pf[4];
            #pragma unroll
            for (int mt = 0; mt < 4; ++mt)
                pf[mt] = *(const bf8*)(pbase + (mt * 16 + c15) * 256 + kbyte);
            #pragma unroll
            for (int mt = 0; mt < 4; ++mt)
                #pragma unroll
                for (int ct = 0; ct < 2; ++ct)
                    acc[mt][ct] = __builtin_amdgcn_mfma_f32_16x16x32_bf16(pf[mt], vf[ki][ct], acc[mt][ct], 0, 0, 0);
        }
    }

    // l: reduce over g-groups, one 16-col partial per wave -> l_s
    #pragma unroll
    for (int mi = 0; mi < 4; ++mi) {
        lrun[mi] += __shfl_xor(lrun[mi], 16);
        lrun[mi] += __shfl_xor(lrun[mi], 32);
    }
    if (lane < 16) {
        #pragma unroll
        for (int mi = 0; mi < 4; ++mi) l_s[w][mi * 16 + lane] = lrun[mi];
    }
    __syncthreads();   // all consume reads of Ps done before acc dump reuses it

    float* accs = (float*)Ps;  // 32 KB reuse for ksh-combine
    if (ksh == 1) {
        #pragma unroll
        for (int mt = 0; mt < 4; ++mt)
            #pragma unroll
            for (int ct = 0; ct < 2; ++ct)
                *(f4*)&accs[(((cq * 8 + mt * 2 + ct) * 64) + lane) * 4] = acc[mt][ct];
    }
    if (w == 0) {
        float sacc = 0.f;
        #pragma unroll
        for (int ww = 0; ww < 8; ++ww) sacc += l_s[ww][lane];
        l_tot[lane] = sacc;
    }
    __syncthreads();
    if (ksh == 0) {
        const float g0 = gamma[0];
        #pragma unroll
        for (int mt = 0; mt < 4; ++mt) {
            float4 lv = *(const float4*)&l_tot[mt * 16 + 4 * g];
            float i0 = 1.f / lv.x, i1 = 1.f / lv.y, i2 = 1.f / lv.z, i3 = 1.f / lv.w;
            #pragma unroll
            for (int ct = 0; ct < 2; ++ct) {
                f4 o = *(const f4*)&accs[(((cq * 8 + mt * 2 + ct) * 64) + lane) * 4];
                f4 a = acc[mt][ct];
                int c = c0 + cq * 32 + ct * 16 + c15;
                size_t base = ((size_t)(b * C_ + c)) * (size_t)N_ + m0 + mt * 16 + 4 * g;
                float4 xv = *(const float4*)(x + base);
                float4 r;
                r.x = g0 * ((a.x + o.x) * i0) + xv.x;
                r.y = g0 * ((a.y + o.y) * i1) + xv.y;
                r.z = g0 * ((a.z + o.z) * i2) + xv.z;
                r.w = g0 * ((a.w + o.w) * i3) + xv.w;
                *(float4*)(out + base) = r;
            }
        }
    }
}

extern "C" void kernel_launch(void* const* d_in, const int* in_sizes, int n_in,
                              void* d_out, int out_size, void* d_ws, size_t ws_size,
                              hipStream_t stream) {
    const float* x     = (const float*)d_in[0];
    const float* Wq    = (const float*)d_in[1];
    const float* bq    = (const float*)d_in[2];
    const float* Wk    = (const float*)d_in[3];
    const float* bk    = (const float*)d_in[4];
    const float* Wv    = (const float*)d_in[5];
    const float* bv    = (const float*)d_in[6];
    const float* gamma = (const float*)d_in[7];
    float* out = (float*)d_out;

    unsigned short* qb   = (unsigned short*)d_ws;
    unsigned short* kb   = qb + (size_t)B_ * N_ * D_;
    unsigned short* vb   = kb + (size_t)B_ * N_ * D_;
    unsigned short* Wqkb = vb + (size_t)B_ * C_ * N_;
    unsigned short* Wvb  = Wqkb + 64 * C_;

    prep<<<256, 256, 0, stream>>>(Wq, Wk, Wv, Wqkb, Wvb);
    qkv<<<dim3(128, 4), 256, 0, stream>>>(x, Wqkb, Wvb, bq, bk, bv, qb, kb, vb);
    attn<<<dim3(512), 512, 0, stream>>>(qb, kb, vb, x, gamma, out);
}